// Round 4
// baseline (885.784 us; speedup 1.0000x reference)
//
#include <hip/hip_runtime.h>
#include <cstddef>
#include <cstdint>

#define B_ 32
#define N_ 8192
#define D_ 64
#define H_ 128
#define S_ 16
// softmax in exp2 domain: logit_e2 = (2*dot - |s|^2) * (1/tau) * log2(e)
#define L2SCALE 14.426950408889634f

typedef unsigned short ushort_t;
typedef __attribute__((ext_vector_type(8))) short short8;
typedef __attribute__((ext_vector_type(4))) float f32x4;

__device__ __forceinline__ float gelu_exact(float x){
    return 0.5f * x * (1.0f + erff(x * 0.70710678118654752f));
}
__device__ __forceinline__ ushort_t f2bf(float f){
    unsigned u = __float_as_uint(f);
    unsigned r = (u + 0x7FFF + ((u >> 16) & 1)) >> 16;   // RNE
    return (ushort_t)r;
}
__device__ __forceinline__ float bf2f(ushort_t h){
    return __uint_as_float(((unsigned)h) << 16);
}

// ---------------------------------------------------------------------------
// Kernel A: feats = LN2( gelu(LN1(x@w1+b1)) @ w2 + b2 ), stored as bf16
// hi/lo split pair (f = hi + lo), row-major [b*n][h].
// ---------------------------------------------------------------------------
__global__ __launch_bounds__(256) void feats_kernel(
    const float* __restrict__ x, const float* __restrict__ w1, const float* __restrict__ b1,
    const float* __restrict__ ln1g, const float* __restrict__ ln1b,
    const float* __restrict__ w2g, const float* __restrict__ b2,
    const float* __restrict__ ln2g, const float* __restrict__ ln2b,
    ushort_t* __restrict__ f_hi, ushort_t* __restrict__ f_lo)
{
    __shared__ float smem[12544];
    float* xs  = smem;                     // [64][68]
    float* w1s = smem + 4352;              // [64][128]
    float* hs  = smem;                     // [64][132]
    float* w2s = smem + 8448;              // [32][128]

    const int tid  = threadIdx.x;
    const int row0 = blockIdx.x * 64;
    const int c0   = (tid & 15) * 8;
    const int r0   = (tid >> 4) * 4;

    for (int i = tid; i < 1024; i += 256){
        int r = i >> 4, c4 = i & 15;
        float4 v = *(const float4*)(x + (size_t)(row0 + r) * 64 + c4 * 4);
        *(float4*)(xs + r * 68 + c4 * 4) = v;
    }
    for (int i = tid; i < 2048; i += 256)
        ((float4*)w1s)[i] = ((const float4*)w1)[i];
    __syncthreads();

    float acc[4][8];
    #pragma unroll
    for (int i=0;i<4;++i){
        #pragma unroll
        for (int j=0;j<8;++j) acc[i][j]=0.f;
    }
    #pragma unroll 4
    for (int d = 0; d < 64; ++d){
        float4 bv0 = *(const float4*)(w1s + d*128 + c0);
        float4 bv1 = *(const float4*)(w1s + d*128 + c0 + 4);
        float bv[8] = {bv0.x,bv0.y,bv0.z,bv0.w,bv1.x,bv1.y,bv1.z,bv1.w};
        float av[4];
        #pragma unroll
        for (int i=0;i<4;++i) av[i] = xs[(r0+i)*68 + d];
        #pragma unroll
        for (int i=0;i<4;++i){
            #pragma unroll
            for (int j=0;j<8;++j) acc[i][j] += av[i]*bv[j];
        }
    }

    float4 bb0 = *(const float4*)(b1 + c0),   bb1 = *(const float4*)(b1 + c0 + 4);
    float4 gg0 = *(const float4*)(ln1g + c0), gg1 = *(const float4*)(ln1g + c0 + 4);
    float4 be0 = *(const float4*)(ln1b + c0), be1 = *(const float4*)(ln1b + c0 + 4);
    float bia[8] = {bb0.x,bb0.y,bb0.z,bb0.w,bb1.x,bb1.y,bb1.z,bb1.w};
    float gam[8] = {gg0.x,gg0.y,gg0.z,gg0.w,gg1.x,gg1.y,gg1.z,gg1.w};
    float bet[8] = {be0.x,be0.y,be0.z,be0.w,be1.x,be1.y,be1.z,be1.w};

    float hrow[4][8];
    #pragma unroll
    for (int i=0;i<4;++i){
        float v[8]; float s1=0.f, sq=0.f;
        #pragma unroll
        for (int j=0;j<8;++j){ v[j] = acc[i][j] + bia[j]; s1 += v[j]; sq += v[j]*v[j]; }
        #pragma unroll
        for (int m=1; m<16; m<<=1){ s1 += __shfl_xor(s1, m); sq += __shfl_xor(sq, m); }
        float mean = s1 * (1.0f/128.0f);
        float var  = sq * (1.0f/128.0f) - mean*mean;
        float rs   = 1.0f / sqrtf(var + 1e-5f);
        #pragma unroll
        for (int j=0;j<8;++j){
            float t = (v[j]-mean)*rs*gam[j] + bet[j];
            hrow[i][j] = gelu_exact(t);
        }
    }
    __syncthreads();
    #pragma unroll
    for (int i=0;i<4;++i){
        *(float4*)(hs + (r0+i)*132 + c0)     = make_float4(hrow[i][0],hrow[i][1],hrow[i][2],hrow[i][3]);
        *(float4*)(hs + (r0+i)*132 + c0 + 4) = make_float4(hrow[i][4],hrow[i][5],hrow[i][6],hrow[i][7]);
    }

    float acc2[4][8];
    #pragma unroll
    for (int i=0;i<4;++i){
        #pragma unroll
        for (int j=0;j<8;++j) acc2[i][j]=0.f;
    }
    for (int ck = 0; ck < 4; ++ck){
        __syncthreads();
        for (int i = tid; i < 1024; i += 256)
            ((float4*)w2s)[i] = ((const float4*)w2g)[ck*1024 + i];
        __syncthreads();
        #pragma unroll 4
        for (int k=0;k<32;++k){
            float4 bv0 = *(const float4*)(w2s + k*128 + c0);
            float4 bv1 = *(const float4*)(w2s + k*128 + c0 + 4);
            float bv[8] = {bv0.x,bv0.y,bv0.z,bv0.w,bv1.x,bv1.y,bv1.z,bv1.w};
            int kk = ck*32 + k;
            float av[4];
            #pragma unroll
            for (int i=0;i<4;++i) av[i] = hs[(r0+i)*132 + kk];
            #pragma unroll
            for (int i=0;i<4;++i){
                #pragma unroll
                for (int j=0;j<8;++j) acc2[i][j] += av[i]*bv[j];
            }
        }
    }

    float4 cb0 = *(const float4*)(b2 + c0),   cb1 = *(const float4*)(b2 + c0 + 4);
    float4 cg0 = *(const float4*)(ln2g + c0), cg1 = *(const float4*)(ln2g + c0 + 4);
    float4 ce0 = *(const float4*)(ln2b + c0), ce1 = *(const float4*)(ln2b + c0 + 4);
    float bia2[8] = {cb0.x,cb0.y,cb0.z,cb0.w,cb1.x,cb1.y,cb1.z,cb1.w};
    float gam2[8] = {cg0.x,cg0.y,cg0.z,cg0.w,cg1.x,cg1.y,cg1.z,cg1.w};
    float bet2[8] = {ce0.x,ce0.y,ce0.z,ce0.w,ce1.x,ce1.y,ce1.z,ce1.w};

    #pragma unroll
    for (int i=0;i<4;++i){
        float v[8]; float s1=0.f, sq=0.f;
        #pragma unroll
        for (int j=0;j<8;++j){ v[j] = acc2[i][j] + bia2[j]; s1 += v[j]; sq += v[j]*v[j]; }
        #pragma unroll
        for (int m=1; m<16; m<<=1){ s1 += __shfl_xor(s1, m); sq += __shfl_xor(sq, m); }
        float mean = s1 * (1.0f/128.0f);
        float var  = sq * (1.0f/128.0f) - mean*mean;
        float rs   = 1.0f / sqrtf(var + 1e-5f);
        short8 vhi, vlo;
        #pragma unroll
        for (int j=0;j<8;++j){
            float o = (v[j]-mean)*rs*gam2[j] + bet2[j];
            ushort_t hi = f2bf(o);
            float lo = o - bf2f(hi);
            vhi[j] = (short)hi;
            vlo[j] = (short)f2bf(lo);
        }
        size_t off = (size_t)(row0 + r0 + i)*128 + c0;
        *(short8*)(f_hi + off) = vhi;
        *(short8*)(f_lo + off) = vlo;
    }
}

__global__ void init_slots(const float* __restrict__ mu, float* __restrict__ slots){
    int i = blockIdx.x * 256 + threadIdx.x;
    slots[i] = mu[i & 2047];
}

// ---------------------------------------------------------------------------
// Kernel B (v4, MFMA): as v3 but PV uses the full 3-term split
//   num^T = fT_hi*(P_hi+P_lo) + fT_lo*P_hi   (fixes R3's 2^-9 f_lo error)
// ---------------------------------------------------------------------------
__global__ __launch_bounds__(256) void attn_kernel(
    const ushort_t* __restrict__ f_hi, const ushort_t* __restrict__ f_lo,
    const float* __restrict__ slots,
    float* __restrict__ num, float* __restrict__ den,
    float* __restrict__ attn_out, const int write_attn)
{
    __shared__ ushort_t fTh[128*136];    // transposed f_hi chunk [h][n], 34816 B
    __shared__ ushort_t fTl[128*136];    // transposed f_lo chunk [h][n], 34816 B
    __shared__ ushort_t P_hi[16*136];    // P[s][n] hi, 4352 B
    __shared__ ushort_t P_lo[16*136];
    __shared__ float    s2buf[16];

    const int tid  = threadIdx.x;
    const int w    = tid >> 6;
    const int l    = tid & 63;
    const int ln   = l & 15;
    const int quad = l >> 4;
    const int b    = blockIdx.x >> 6;
    const int n0   = (blockIdx.x & 63) * 128;

    // ---- slots A-fragments (hi/lo) + |s|^2 ----
    short8 sa_hi[4], sa_lo[4];
    float q2 = 0.f;
    {
        const float* sp = slots + ((size_t)(b*16 + ln))*128 + quad*8;
        #pragma unroll
        for (int ks=0; ks<4; ++ks){
            float4 v0 = *(const float4*)(sp + ks*32);
            float4 v1 = *(const float4*)(sp + ks*32 + 4);
            float v[8] = {v0.x,v0.y,v0.z,v0.w,v1.x,v1.y,v1.z,v1.w};
            #pragma unroll
            for (int j=0;j<8;++j){
                q2 += v[j]*v[j];
                ushort_t hi = f2bf(v[j]);
                float lo = v[j] - bf2f(hi);
                sa_hi[ks][j] = (short)hi;
                sa_lo[ks][j] = (short)f2bf(lo);
            }
        }
    }
    q2 += __shfl_xor(q2, 16);
    q2 += __shfl_xor(q2, 32);
    if (tid < 16) s2buf[tid] = q2;       // wave 0, quad 0: lane ln==tid holds s2(tid)
    __syncthreads();

    float s2v[4];
    #pragma unroll
    for (int r=0;r<4;++r) s2v[r] = s2buf[quad*4 + r];

    // ---- phase 1: logits + softmax + P/fT staging ----
    float den_acc[4] = {0.f,0.f,0.f,0.f};
    const size_t fbase = (size_t)b*N_ + n0;

    #pragma unroll
    for (int t2=0; t2<2; ++t2){
        const int t  = w*2 + t2;
        const int nl = t*16 + ln;                 // n-local in [0,128)
        const size_t rowoff = (fbase + nl) * 128;

        short8 fh[4], fl[4];
        #pragma unroll
        for (int ks=0; ks<4; ++ks){
            fh[ks] = *(const short8*)(f_hi + rowoff + ks*32 + quad*8);
            fl[ks] = *(const short8*)(f_lo + rowoff + ks*32 + quad*8);
        }
        // transpose f_hi / f_lo fragments into LDS fT[h][n]
        #pragma unroll
        for (int ks=0; ks<4; ++ks){
            #pragma unroll
            for (int j=0;j<8;++j){
                fTh[(ks*32 + quad*8 + j)*136 + nl] = (ushort_t)fh[ks][j];
                fTl[(ks*32 + quad*8 + j)*136 + nl] = (ushort_t)fl[ks][j];
            }
        }

        f32x4 d = {0.f,0.f,0.f,0.f};
        #pragma unroll
        for (int ks=0;ks<4;++ks) d = __builtin_amdgcn_mfma_f32_16x16x32_bf16(sa_hi[ks], fh[ks], d, 0,0,0);
        #pragma unroll
        for (int ks=0;ks<4;++ks) d = __builtin_amdgcn_mfma_f32_16x16x32_bf16(sa_hi[ks], fl[ks], d, 0,0,0);
        #pragma unroll
        for (int ks=0;ks<4;++ks) d = __builtin_amdgcn_mfma_f32_16x16x32_bf16(sa_lo[ks], fh[ks], d, 0,0,0);

        // D layout: col(n)=ln, row(s)=quad*4+r
        float L[4];
        #pragma unroll
        for (int r=0;r<4;++r) L[r] = (2.f*d[r] - s2v[r]) * L2SCALE;
        float mx = fmaxf(fmaxf(L[0],L[1]), fmaxf(L[2],L[3]));
        mx = fmaxf(mx, __shfl_xor(mx, 16));
        mx = fmaxf(mx, __shfl_xor(mx, 32));
        float e[4];
        float z = 0.f;
        #pragma unroll
        for (int r=0;r<4;++r){ e[r] = exp2f(L[r] - mx); z += e[r]; }
        z += __shfl_xor(z, 16);
        z += __shfl_xor(z, 32);
        float rz = 1.f / z;
        #pragma unroll
        for (int r=0;r<4;++r){
            float p = e[r] * rz;
            den_acc[r] += p;
            if (write_attn)
                attn_out[((size_t)(b*16 + quad*4 + r))*N_ + n0 + nl] = p;
            ushort_t ph = f2bf(p);
            float plr = p - bf2f(ph);
            P_hi[(quad*4+r)*136 + nl] = ph;
            P_lo[(quad*4+r)*136 + nl] = f2bf(plr);
        }
    }
    __syncthreads();

    // ---- phase 2: num^T[h][s] += fT_hi*(P_hi+P_lo) + fT_lo*P_hi ----
    #pragma unroll
    for (int t2=0; t2<2; ++t2){
        const int ht = w*2 + t2;
        f32x4 d = {0.f,0.f,0.f,0.f};
        #pragma unroll
        for (int ks=0; ks<4; ++ks){
            short8 fah = *(const short8*)(&fTh[(ht*16 + ln)*136 + ks*32 + quad*8]);
            short8 fal = *(const short8*)(&fTl[(ht*16 + ln)*136 + ks*32 + quad*8]);
            short8 pbh = *(const short8*)(&P_hi[ln*136 + ks*32 + quad*8]);
            short8 pbl = *(const short8*)(&P_lo[ln*136 + ks*32 + quad*8]);
            d = __builtin_amdgcn_mfma_f32_16x16x32_bf16(fah, pbh, d, 0,0,0);
            d = __builtin_amdgcn_mfma_f32_16x16x32_bf16(fah, pbl, d, 0,0,0);
            d = __builtin_amdgcn_mfma_f32_16x16x32_bf16(fal, pbh, d, 0,0,0);
        }
        // D layout: col(s)=ln, row(h-in-tile)=quad*4+r
        #pragma unroll
        for (int r=0;r<4;++r)
            atomicAdd(&num[((size_t)b*16 + ln)*128 + ht*16 + quad*4 + r], d[r]);
    }

    // den: reduce over n (lane&15 dim), then one atomic per (wave, s)
    #pragma unroll
    for (int m=1; m<16; m<<=1){
        #pragma unroll
        for (int r=0;r<4;++r) den_acc[r] += __shfl_xor(den_acc[r], m);
    }
    if (ln == 0){
        #pragma unroll
        for (int r=0;r<4;++r) atomicAdd(&den[b*16 + quad*4 + r], den_acc[r]);
    }
}

// ---------------------------------------------------------------------------
// Kernel C: slot update (GRU + LN + MLP), unchanged.
// ---------------------------------------------------------------------------
__global__ __launch_bounds__(256) void update_kernel(
    const float* __restrict__ num, const float* __restrict__ den,
    float* __restrict__ slots,
    const float* __restrict__ gwi, const float* __restrict__ gwh,
    const float* __restrict__ gbi, const float* __restrict__ gbh,
    const float* __restrict__ mw1, const float* __restrict__ mb1,
    const float* __restrict__ mw2, const float* __restrict__ mb2,
    const float* __restrict__ ng, const float* __restrict__ nbv,
    float* __restrict__ out_slots, const int write_out)
{
    __shared__ float us[512], sl[512], gbuf[3072], nbuf[512], lnb[512], qb[512];
    const int tid  = threadIdx.x;
    const int row0 = blockIdx.x * 4;

    for (int i = tid; i < 512; i += 256){
        int r = i >> 7, h = i & 127;
        int grow = row0 + r;
        float dv = den[grow] + 1e-8f;
        us[i] = num[(size_t)grow*128 + h] / dv;
        sl[i] = slots[(size_t)grow*128 + h];
    }
    __syncthreads();

    for (int idx = tid; idx < 3072; idx += 256){
        int which = idx >= 1536;
        int rem   = idx - which*1536;
        int r     = rem / 384;
        int o     = rem - r*384;
        const float* W   = which ? gwh : gwi;
        const float* bb  = which ? gbh : gbi;
        const float* src = (which ? sl : us) + r*128;
        float a = bb[o];
        const float4* Wr = (const float4*)(W + (size_t)o*128);
        #pragma unroll 8
        for (int k4=0;k4<32;++k4){
            float4 wv = Wr[k4];
            float4 sv = *(const float4*)(src + 4*k4);
            a += sv.x*wv.x + sv.y*wv.y + sv.z*wv.z + sv.w*wv.w;
        }
        gbuf[idx] = a;
    }
    __syncthreads();

    for (int i = tid; i < 512; i += 256){
        int r = i >> 7, h = i & 127;
        float ir  = gbuf[r*384 + h];
        float iz  = gbuf[r*384 + 128 + h];
        float in_ = gbuf[r*384 + 256 + h];
        float hr  = gbuf[1536 + r*384 + h];
        float hz  = gbuf[1536 + r*384 + 128 + h];
        float hn  = gbuf[1536 + r*384 + 256 + h];
        float rg = 1.f/(1.f + expf(-(ir+hr)));
        float zg = 1.f/(1.f + expf(-(iz+hz)));
        float nn = tanhf(in_ + rg*hn);
        nbuf[i] = (1.f - zg)*nn + zg*sl[i];
    }
    __syncthreads();

    {
        int wv = tid >> 6, ll = tid & 63;
        float v0 = nbuf[wv*128 + ll], v1 = nbuf[wv*128 + 64 + ll];
        float s1 = v0 + v1, sq = v0*v0 + v1*v1;
        #pragma unroll
        for (int m=1; m<64; m<<=1){ s1 += __shfl_xor(s1,m); sq += __shfl_xor(sq,m); }
        float mean = s1*(1.f/128.f), var = sq*(1.f/128.f) - mean*mean;
        float rs = 1.f/sqrtf(var + 1e-5f);
        lnb[wv*128 + ll]      = (v0-mean)*rs*ng[ll] + nbv[ll];
        lnb[wv*128 + 64 + ll] = (v1-mean)*rs*ng[64+ll] + nbv[64+ll];
    }
    __syncthreads();

    for (int i = tid; i < 512; i += 256){
        int r = i >> 7, o = i & 127;
        float a = mb1[o];
        const float* lr = lnb + r*128;
        #pragma unroll 8
        for (int k=0;k<128;++k) a += lr[k] * mw1[(size_t)k*128 + o];
        qb[i] = gelu_exact(a);
    }
    __syncthreads();

    for (int i = tid; i < 512; i += 256){
        int r = i >> 7, h = i & 127;
        float a = mb2[h];
        const float* qr = qb + r*128;
        #pragma unroll 8
        for (int k=0;k<128;++k) a += qr[k] * mw2[(size_t)k*128 + h];
        float ov = nbuf[i] + 0.2f*a;
        int grow = row0 + r;
        slots[(size_t)grow*128 + h] = ov;
        if (write_out) out_slots[(size_t)grow*128 + h] = ov;
    }
}

// ---------------------------------------------------------------------------
extern "C" void kernel_launch(void* const* d_in, const int* in_sizes, int n_in,
                              void* d_out, int out_size, void* d_ws, size_t ws_size,
                              hipStream_t stream)
{
    const float* x    = (const float*)d_in[0];
    const float* w1   = (const float*)d_in[1];
    const float* b1   = (const float*)d_in[2];
    const float* ln1g = (const float*)d_in[3];
    const float* ln1b = (const float*)d_in[4];
    const float* w2   = (const float*)d_in[5];
    const float* b2   = (const float*)d_in[6];
    const float* ln2g = (const float*)d_in[7];
    const float* ln2b = (const float*)d_in[8];
    const float* smu  = (const float*)d_in[9];
    const float* gwi  = (const float*)d_in[10];
    const float* gwh  = (const float*)d_in[11];
    const float* gbi  = (const float*)d_in[12];
    const float* gbh  = (const float*)d_in[13];
    const float* mw1  = (const float*)d_in[14];
    const float* mb1  = (const float*)d_in[15];
    const float* mw2  = (const float*)d_in[16];
    const float* mb2  = (const float*)d_in[17];
    const float* ng   = (const float*)d_in[18];
    const float* nbv  = (const float*)d_in[19];

    float* out_slots = (float*)d_out;
    float* out_attn  = (float*)d_out + (size_t)B_*S_*H_;

    // workspace: f_hi/f_lo bf16 (2 x 64 MB), then fp32 slots/num/den
    ushort_t* f_hi = (ushort_t*)d_ws;
    ushort_t* f_lo = f_hi + (size_t)B_*N_*H_;
    float* slots = (float*)(f_lo + (size_t)B_*N_*H_);
    float* num   = slots + B_*S_*H_;
    float* den   = num + B_*S_*H_;

    feats_kernel<<<dim3(4096), dim3(256), 0, stream>>>(
        x, w1, b1, ln1g, ln1b, w2, b2, ln2g, ln2b, f_hi, f_lo);
    init_slots<<<dim3(256), dim3(256), 0, stream>>>(smu, slots);

    for (int it = 0; it < 3; ++it){
        hipMemsetAsync(num, 0, (size_t)(B_*S_*H_ + B_*S_)*sizeof(float), stream);
        attn_kernel<<<dim3(2048), dim3(256), 0, stream>>>(
            f_hi, f_lo, slots, num, den, out_attn, (it==2) ? 1 : 0);
        update_kernel<<<dim3(128), dim3(256), 0, stream>>>(
            num, den, slots, gwi, gwh, gbi, gbh, mw1, mb1, mw2, mb2, ng, nbv,
            out_slots, (it==2) ? 1 : 0);
    }
}

// Round 5
// 651.454 us; speedup vs baseline: 1.3597x; 1.3597x over previous
//
#include <hip/hip_runtime.h>
#include <cstddef>
#include <cstdint>

#define B_ 32
#define N_ 8192
#define D_ 64
#define H_ 128
#define S_ 16
// softmax in exp2 domain: logit_e2 = (2*dot - |s|^2) * (1/tau) * log2(e)
#define L2SCALE 14.426950408889634f

typedef unsigned short ushort_t;
typedef __attribute__((ext_vector_type(8))) short short8;
typedef __attribute__((ext_vector_type(4))) float f32x4;

#define NCHUNK 512                 // n per attn block
#define NBLK   (N_ / NCHUNK)       // 16 chunks per batch
#define PSTRIDE 520                // P row stride in shorts (512 + 8, mult of 8)

__device__ __forceinline__ float gelu_exact(float x){
    return 0.5f * x * (1.0f + erff(x * 0.70710678118654752f));
}
__device__ __forceinline__ ushort_t f2bf(float f){
    unsigned u = __float_as_uint(f);
    unsigned r = (u + 0x7FFF + ((u >> 16) & 1)) >> 16;   // RNE
    return (ushort_t)r;
}
__device__ __forceinline__ float bf2f(ushort_t h){
    return __uint_as_float(((unsigned)h) << 16);
}

// ---------------------------------------------------------------------------
// Kernel A: feats = LN2( gelu(LN1(x@w1+b1)) @ w2 + b2 ), stored as bf16
// hi/lo split pair (f = hi + lo), row-major [b*n][h].  (unchanged from R4)
// ---------------------------------------------------------------------------
__global__ __launch_bounds__(256) void feats_kernel(
    const float* __restrict__ x, const float* __restrict__ w1, const float* __restrict__ b1,
    const float* __restrict__ ln1g, const float* __restrict__ ln1b,
    const float* __restrict__ w2g, const float* __restrict__ b2,
    const float* __restrict__ ln2g, const float* __restrict__ ln2b,
    ushort_t* __restrict__ f_hi, ushort_t* __restrict__ f_lo)
{
    __shared__ float smem[12544];
    float* xs  = smem;                     // [64][68]
    float* w1s = smem + 4352;              // [64][128]
    float* hs  = smem;                     // [64][132]
    float* w2s = smem + 8448;              // [32][128]

    const int tid  = threadIdx.x;
    const int row0 = blockIdx.x * 64;
    const int c0   = (tid & 15) * 8;
    const int r0   = (tid >> 4) * 4;

    for (int i = tid; i < 1024; i += 256){
        int r = i >> 4, c4 = i & 15;
        float4 v = *(const float4*)(x + (size_t)(row0 + r) * 64 + c4 * 4);
        *(float4*)(xs + r * 68 + c4 * 4) = v;
    }
    for (int i = tid; i < 2048; i += 256)
        ((float4*)w1s)[i] = ((const float4*)w1)[i];
    __syncthreads();

    float acc[4][8];
    #pragma unroll
    for (int i=0;i<4;++i){
        #pragma unroll
        for (int j=0;j<8;++j) acc[i][j]=0.f;
    }
    #pragma unroll 4
    for (int d = 0; d < 64; ++d){
        float4 bv0 = *(const float4*)(w1s + d*128 + c0);
        float4 bv1 = *(const float4*)(w1s + d*128 + c0 + 4);
        float bv[8] = {bv0.x,bv0.y,bv0.z,bv0.w,bv1.x,bv1.y,bv1.z,bv1.w};
        float av[4];
        #pragma unroll
        for (int i=0;i<4;++i) av[i] = xs[(r0+i)*68 + d];
        #pragma unroll
        for (int i=0;i<4;++i){
            #pragma unroll
            for (int j=0;j<8;++j) acc[i][j] += av[i]*bv[j];
        }
    }

    float4 bb0 = *(const float4*)(b1 + c0),   bb1 = *(const float4*)(b1 + c0 + 4);
    float4 gg0 = *(const float4*)(ln1g + c0), gg1 = *(const float4*)(ln1g + c0 + 4);
    float4 be0 = *(const float4*)(ln1b + c0), be1 = *(const float4*)(ln1b + c0 + 4);
    float bia[8] = {bb0.x,bb0.y,bb0.z,bb0.w,bb1.x,bb1.y,bb1.z,bb1.w};
    float gam[8] = {gg0.x,gg0.y,gg0.z,gg0.w,gg1.x,gg1.y,gg1.z,gg1.w};
    float bet[8] = {be0.x,be0.y,be0.z,be0.w,be1.x,be1.y,be1.z,be1.w};

    float hrow[4][8];
    #pragma unroll
    for (int i=0;i<4;++i){
        float v[8]; float s1=0.f, sq=0.f;
        #pragma unroll
        for (int j=0;j<8;++j){ v[j] = acc[i][j] + bia[j]; s1 += v[j]; sq += v[j]*v[j]; }
        #pragma unroll
        for (int m=1; m<16; m<<=1){ s1 += __shfl_xor(s1, m); sq += __shfl_xor(sq, m); }
        float mean = s1 * (1.0f/128.0f);
        float var  = sq * (1.0f/128.0f) - mean*mean;
        float rs   = 1.0f / sqrtf(var + 1e-5f);
        #pragma unroll
        for (int j=0;j<8;++j){
            float t = (v[j]-mean)*rs*gam[j] + bet[j];
            hrow[i][j] = gelu_exact(t);
        }
    }
    __syncthreads();
    #pragma unroll
    for (int i=0;i<4;++i){
        *(float4*)(hs + (r0+i)*132 + c0)     = make_float4(hrow[i][0],hrow[i][1],hrow[i][2],hrow[i][3]);
        *(float4*)(hs + (r0+i)*132 + c0 + 4) = make_float4(hrow[i][4],hrow[i][5],hrow[i][6],hrow[i][7]);
    }

    float acc2[4][8];
    #pragma unroll
    for (int i=0;i<4;++i){
        #pragma unroll
        for (int j=0;j<8;++j) acc2[i][j]=0.f;
    }
    for (int ck = 0; ck < 4; ++ck){
        __syncthreads();
        for (int i = tid; i < 1024; i += 256)
            ((float4*)w2s)[i] = ((const float4*)w2g)[ck*1024 + i];
        __syncthreads();
        #pragma unroll 4
        for (int k=0;k<32;++k){
            float4 bv0 = *(const float4*)(w2s + k*128 + c0);
            float4 bv1 = *(const float4*)(w2s + k*128 + c0 + 4);
            float bv[8] = {bv0.x,bv0.y,bv0.z,bv0.w,bv1.x,bv1.y,bv1.z,bv1.w};
            int kk = ck*32 + k;
            float av[4];
            #pragma unroll
            for (int i=0;i<4;++i) av[i] = hs[(r0+i)*132 + kk];
            #pragma unroll
            for (int i=0;i<4;++i){
                #pragma unroll
                for (int j=0;j<8;++j) acc2[i][j] += av[i]*bv[j];
            }
        }
    }

    float4 cb0 = *(const float4*)(b2 + c0),   cb1 = *(const float4*)(b2 + c0 + 4);
    float4 cg0 = *(const float4*)(ln2g + c0), cg1 = *(const float4*)(ln2g + c0 + 4);
    float4 ce0 = *(const float4*)(ln2b + c0), ce1 = *(const float4*)(ln2b + c0 + 4);
    float bia2[8] = {cb0.x,cb0.y,cb0.z,cb0.w,cb1.x,cb1.y,cb1.z,cb1.w};
    float gam2[8] = {cg0.x,cg0.y,cg0.z,cg0.w,cg1.x,cg1.y,cg1.z,cg1.w};
    float bet2[8] = {ce0.x,ce0.y,ce0.z,ce0.w,ce1.x,ce1.y,ce1.z,ce1.w};

    #pragma unroll
    for (int i=0;i<4;++i){
        float v[8]; float s1=0.f, sq=0.f;
        #pragma unroll
        for (int j=0;j<8;++j){ v[j] = acc2[i][j] + bia2[j]; s1 += v[j]; sq += v[j]*v[j]; }
        #pragma unroll
        for (int m=1; m<16; m<<=1){ s1 += __shfl_xor(s1, m); sq += __shfl_xor(sq, m); }
        float mean = s1 * (1.0f/128.0f);
        float var  = sq * (1.0f/128.0f) - mean*mean;
        float rs   = 1.0f / sqrtf(var + 1e-5f);
        short8 vhi, vlo;
        #pragma unroll
        for (int j=0;j<8;++j){
            float o = (v[j]-mean)*rs*gam2[j] + bet2[j];
            ushort_t hi = f2bf(o);
            float lo = o - bf2f(hi);
            vhi[j] = (short)hi;
            vlo[j] = (short)f2bf(lo);
        }
        size_t off = (size_t)(row0 + r0 + i)*128 + c0;
        *(short8*)(f_hi + off) = vhi;
        *(short8*)(f_lo + off) = vlo;
    }
}

__global__ void init_slots(const float* __restrict__ mu, float* __restrict__ slots){
    int i = blockIdx.x * 256 + threadIdx.x;
    slots[i] = mu[i & 2047];
}

// ---------------------------------------------------------------------------
// Kernel B (v5): 512 threads (8 waves), 512-n chunk per block, grid 512.
// NO global atomics (per-block partials), NO LDS transpose (PV uses P as the
// A operand from its natural [s][n] LDS layout; F gathered from global/L2).
// Phase 1: wave w owns n-tiles w*4..w*4+3: logits via 12 MFMA (3-term split),
//   softmax in D-layout, P -> LDS (hi/lo).
// Phase 2: wave w owns h-tile w: num[s][h] = P_hi*F_hi + P_lo*F_hi + P_hi*F_lo,
//   48 MFMA into one f32x4; plain stores of partials to scratch.
// ---------------------------------------------------------------------------
__global__ __launch_bounds__(512, 4) void attn_kernel(
    const ushort_t* __restrict__ f_hi, const ushort_t* __restrict__ f_lo,
    const float* __restrict__ slots,
    float* __restrict__ pn, float* __restrict__ pd,
    float* __restrict__ attn_out, const int write_attn)
{
    __shared__ ushort_t P_hi[16*PSTRIDE];   // 16640 B
    __shared__ ushort_t P_lo[16*PSTRIDE];   // 16640 B
    __shared__ float    s2buf[16];
    __shared__ float    den_red[16];

    const int tid  = threadIdx.x;
    const int w    = tid >> 6;
    const int l    = tid & 63;
    const int ln   = l & 15;
    const int quad = l >> 4;
    const int b    = blockIdx.x >> 4;
    const int nc   = blockIdx.x & 15;
    const int n0   = nc * NCHUNK;

    if (tid < 16) den_red[tid] = 0.f;

    // ---- slots A-fragments (hi/lo) + |s|^2 ----
    short8 sa_hi[4], sa_lo[4];
    float q2 = 0.f;
    {
        const float* sp = slots + ((size_t)(b*16 + ln))*128 + quad*8;
        #pragma unroll
        for (int ks=0; ks<4; ++ks){
            float4 v0 = *(const float4*)(sp + ks*32);
            float4 v1 = *(const float4*)(sp + ks*32 + 4);
            float v[8] = {v0.x,v0.y,v0.z,v0.w,v1.x,v1.y,v1.z,v1.w};
            #pragma unroll
            for (int j=0;j<8;++j){
                q2 += v[j]*v[j];
                ushort_t hi = f2bf(v[j]);
                float lo = v[j] - bf2f(hi);
                sa_hi[ks][j] = (short)hi;
                sa_lo[ks][j] = (short)f2bf(lo);
            }
        }
    }
    q2 += __shfl_xor(q2, 16);
    q2 += __shfl_xor(q2, 32);
    if (tid < 16) s2buf[tid] = q2;   // wave 0, quad 0: lane ln==tid holds s2(tid)
    __syncthreads();

    float s2v[4];
    #pragma unroll
    for (int r=0;r<4;++r) s2v[r] = s2buf[quad*4 + r];

    // ---- phase 1: logits + softmax + P staging ----
    float den_acc[4] = {0.f,0.f,0.f,0.f};
    const size_t fbase = (size_t)b*N_ + n0;

    #pragma unroll
    for (int t2=0; t2<4; ++t2){
        const int t  = w*4 + t2;
        const int nl = t*16 + ln;                 // n-local in [0,512)
        const size_t rowoff = (fbase + nl) * 128;

        short8 fh[4], fl[4];
        #pragma unroll
        for (int ks=0; ks<4; ++ks){
            fh[ks] = *(const short8*)(f_hi + rowoff + ks*32 + quad*8);
            fl[ks] = *(const short8*)(f_lo + rowoff + ks*32 + quad*8);
        }

        f32x4 d = {0.f,0.f,0.f,0.f};
        #pragma unroll
        for (int ks=0;ks<4;++ks) d = __builtin_amdgcn_mfma_f32_16x16x32_bf16(sa_hi[ks], fh[ks], d, 0,0,0);
        #pragma unroll
        for (int ks=0;ks<4;++ks) d = __builtin_amdgcn_mfma_f32_16x16x32_bf16(sa_hi[ks], fl[ks], d, 0,0,0);
        #pragma unroll
        for (int ks=0;ks<4;++ks) d = __builtin_amdgcn_mfma_f32_16x16x32_bf16(sa_lo[ks], fh[ks], d, 0,0,0);

        // D layout: col(n)=ln, row(s)=quad*4+r
        float L[4];
        #pragma unroll
        for (int r=0;r<4;++r) L[r] = (2.f*d[r] - s2v[r]) * L2SCALE;
        float mx = fmaxf(fmaxf(L[0],L[1]), fmaxf(L[2],L[3]));
        mx = fmaxf(mx, __shfl_xor(mx, 16));
        mx = fmaxf(mx, __shfl_xor(mx, 32));
        float e[4];
        float z = 0.f;
        #pragma unroll
        for (int r=0;r<4;++r){ e[r] = exp2f(L[r] - mx); z += e[r]; }
        z += __shfl_xor(z, 16);
        z += __shfl_xor(z, 32);
        float rz = 1.f / z;
        #pragma unroll
        for (int r=0;r<4;++r){
            float p = e[r] * rz;
            den_acc[r] += p;
            if (write_attn)
                attn_out[((size_t)(b*16 + quad*4 + r))*N_ + n0 + nl] = p;
            ushort_t ph = f2bf(p);
            float plr = p - bf2f(ph);
            P_hi[(quad*4+r)*PSTRIDE + nl] = ph;
            P_lo[(quad*4+r)*PSTRIDE + nl] = f2bf(plr);
        }
    }

    // den: reduce over ln (the n dim within this lane-group), LDS-accumulate
    #pragma unroll
    for (int m=1; m<16; m<<=1){
        #pragma unroll
        for (int r=0;r<4;++r) den_acc[r] += __shfl_xor(den_acc[r], m);
    }
    if (ln == 0){
        #pragma unroll
        for (int r=0;r<4;++r) atomicAdd(&den_red[quad*4 + r], den_acc[r]);
    }
    __syncthreads();

    // ---- phase 2: num[s][h] partial, wave w owns h-tile w ----
    f32x4 dacc = {0.f,0.f,0.f,0.f};
    #pragma unroll 2
    for (int ks=0; ks<16; ++ks){
        short8 pah = *(const short8*)(&P_hi[ln*PSTRIDE + ks*32 + quad*8]);
        short8 pal = *(const short8*)(&P_lo[ln*PSTRIDE + ks*32 + quad*8]);
        short8 fbh, fbl;
        #pragma unroll
        for (int j=0;j<8;++j){
            size_t go = (fbase + (size_t)(ks*32 + quad*8 + j))*128 + w*16 + ln;
            fbh[j] = (short)f_hi[go];
            fbl[j] = (short)f_lo[go];
        }
        dacc = __builtin_amdgcn_mfma_f32_16x16x32_bf16(pah, fbh, dacc, 0,0,0);
        dacc = __builtin_amdgcn_mfma_f32_16x16x32_bf16(pal, fbh, dacc, 0,0,0);
        dacc = __builtin_amdgcn_mfma_f32_16x16x32_bf16(pah, fbl, dacc, 0,0,0);
    }
    // D layout: col(h-in-tile)=ln, row(s)=quad*4+r  -> plain stores to scratch
    {
        float* dst = pn + (size_t)blockIdx.x * 2048;
        #pragma unroll
        for (int r=0;r<4;++r)
            dst[(quad*4+r)*128 + w*16 + ln] = dacc[r];
    }
    if (tid < 16) pd[blockIdx.x*16 + tid] = den_red[tid];
}

// ---------------------------------------------------------------------------
// Kernel C: slot update (GRU + LN + MLP) + fold of the 16 per-chunk partials.
// ---------------------------------------------------------------------------
__global__ __launch_bounds__(256) void update_kernel(
    const float* __restrict__ pn, const float* __restrict__ pd,
    float* __restrict__ slots,
    const float* __restrict__ gwi, const float* __restrict__ gwh,
    const float* __restrict__ gbi, const float* __restrict__ gbh,
    const float* __restrict__ mw1, const float* __restrict__ mb1,
    const float* __restrict__ mw2, const float* __restrict__ mb2,
    const float* __restrict__ ng, const float* __restrict__ nbv,
    float* __restrict__ out_slots, const int write_out)
{
    __shared__ float us[512], sl[512], gbuf[3072], nbuf[512], lnb[512], qb[512];
    const int tid  = threadIdx.x;
    const int row0 = blockIdx.x * 4;

    for (int i = tid; i < 512; i += 256){
        int r = i >> 7, h = i & 127;
        int grow = row0 + r;
        int bb = grow >> 4, ss = grow & 15;
        float sum = 0.f, dv = 0.f;
        #pragma unroll 4
        for (int c = 0; c < NBLK; ++c)
            sum += pn[((size_t)(bb*NBLK + c))*2048 + ss*128 + h];
        #pragma unroll
        for (int c = 0; c < NBLK; ++c)
            dv += pd[(bb*NBLK + c)*16 + ss];
        us[i] = sum / (dv + 1e-8f);
        sl[i] = slots[(size_t)grow*128 + h];
    }
    __syncthreads();

    for (int idx = tid; idx < 3072; idx += 256){
        int which = idx >= 1536;
        int rem   = idx - which*1536;
        int r     = rem / 384;
        int o     = rem - r*384;
        const float* W   = which ? gwh : gwi;
        const float* bb  = which ? gbh : gbi;
        const float* src = (which ? sl : us) + r*128;
        float a = bb[o];
        const float4* Wr = (const float4*)(W + (size_t)o*128);
        #pragma unroll 8
        for (int k4=0;k4<32;++k4){
            float4 wv = Wr[k4];
            float4 sv = *(const float4*)(src + 4*k4);
            a += sv.x*wv.x + sv.y*wv.y + sv.z*wv.z + sv.w*wv.w;
        }
        gbuf[idx] = a;
    }
    __syncthreads();

    for (int i = tid; i < 512; i += 256){
        int r = i >> 7, h = i & 127;
        float ir  = gbuf[r*384 + h];
        float iz  = gbuf[r*384 + 128 + h];
        float in_ = gbuf[r*384 + 256 + h];
        float hr  = gbuf[1536 + r*384 + h];
        float hz  = gbuf[1536 + r*384 + 128 + h];
        float hn  = gbuf[1536 + r*384 + 256 + h];
        float rg = 1.f/(1.f + expf(-(ir+hr)));
        float zg = 1.f/(1.f + expf(-(iz+hz)));
        float nn = tanhf(in_ + rg*hn);
        nbuf[i] = (1.f - zg)*nn + zg*sl[i];
    }
    __syncthreads();

    {
        int wv = tid >> 6, ll = tid & 63;
        float v0 = nbuf[wv*128 + ll], v1 = nbuf[wv*128 + 64 + ll];
        float s1 = v0 + v1, sq = v0*v0 + v1*v1;
        #pragma unroll
        for (int m=1; m<64; m<<=1){ s1 += __shfl_xor(s1,m); sq += __shfl_xor(sq,m); }
        float mean = s1*(1.f/128.f), var = sq*(1.f/128.f) - mean*mean;
        float rs = 1.f/sqrtf(var + 1e-5f);
        lnb[wv*128 + ll]      = (v0-mean)*rs*ng[ll] + nbv[ll];
        lnb[wv*128 + 64 + ll] = (v1-mean)*rs*ng[64+ll] + nbv[64+ll];
    }
    __syncthreads();

    for (int i = tid; i < 512; i += 256){
        int r = i >> 7, o = i & 127;
        float a = mb1[o];
        const float* lr = lnb + r*128;
        #pragma unroll 8
        for (int k=0;k<128;++k) a += lr[k] * mw1[(size_t)k*128 + o];
        qb[i] = gelu_exact(a);
    }
    __syncthreads();

    for (int i = tid; i < 512; i += 256){
        int r = i >> 7, h = i & 127;
        float a = mb2[h];
        const float* qr = qb + r*128;
        #pragma unroll 8
        for (int k=0;k<128;++k) a += qr[k] * mw2[(size_t)k*128 + h];
        float ov = nbuf[i] + 0.2f*a;
        int grow = row0 + r;
        slots[(size_t)grow*128 + h] = ov;
        if (write_out) out_slots[(size_t)grow*128 + h] = ov;
    }
}

// ---------------------------------------------------------------------------
extern "C" void kernel_launch(void* const* d_in, const int* in_sizes, int n_in,
                              void* d_out, int out_size, void* d_ws, size_t ws_size,
                              hipStream_t stream)
{
    const float* x    = (const float*)d_in[0];
    const float* w1   = (const float*)d_in[1];
    const float* b1   = (const float*)d_in[2];
    const float* ln1g = (const float*)d_in[3];
    const float* ln1b = (const float*)d_in[4];
    const float* w2   = (const float*)d_in[5];
    const float* b2   = (const float*)d_in[6];
    const float* ln2g = (const float*)d_in[7];
    const float* ln2b = (const float*)d_in[8];
    const float* smu  = (const float*)d_in[9];
    const float* gwi  = (const float*)d_in[10];
    const float* gwh  = (const float*)d_in[11];
    const float* gbi  = (const float*)d_in[12];
    const float* gbh  = (const float*)d_in[13];
    const float* mw1  = (const float*)d_in[14];
    const float* mb1  = (const float*)d_in[15];
    const float* mw2  = (const float*)d_in[16];
    const float* mb2  = (const float*)d_in[17];
    const float* ng   = (const float*)d_in[18];
    const float* nbv  = (const float*)d_in[19];

    float* out_slots = (float*)d_out;
    float* out_attn  = (float*)d_out + (size_t)B_*S_*H_;

    // workspace: f_hi/f_lo bf16 (2 x 67 MB), slots, per-block partials
    ushort_t* f_hi = (ushort_t*)d_ws;
    ushort_t* f_lo = f_hi + (size_t)B_*N_*H_;
    float* slots = (float*)(f_lo + (size_t)B_*N_*H_);
    float* pn    = slots + B_*S_*H_;                 // [512 blocks][2048]
    float* pd    = pn + (size_t)(B_*NBLK)*2048;      // [512 blocks][16]

    feats_kernel<<<dim3(4096), dim3(256), 0, stream>>>(
        x, w1, b1, ln1g, ln1b, w2, b2, ln2g, ln2b, f_hi, f_lo);
    init_slots<<<dim3(256), dim3(256), 0, stream>>>(smu, slots);

    for (int it = 0; it < 3; ++it){
        attn_kernel<<<dim3(B_*NBLK), dim3(512), 0, stream>>>(
            f_hi, f_lo, slots, pn, pd, out_attn, (it==2) ? 1 : 0);
        update_kernel<<<dim3(128), dim3(256), 0, stream>>>(
            pn, pd, slots, gwi, gwh, gbi, gbh, mw1, mb1, mw2, mb2, ng, nbv,
            out_slots, (it==2) ? 1 : 0);
    }
}